// Round 10
// baseline (182.646 us; speedup 1.0000x reference)
//
#include <hip/hip_runtime.h>
#include <hip/hip_bf16.h>

// Problem constants (b=2, l=4, n=1024, dim=512, heads=8, dh=64, nsample=8)
// All d_in / d_out buffers are FLOAT32 (reference dtypes). Internal compute
// uses bf16 MFMA + fp8(e4m3) K/V gather (bf16-mode absmax threshold 0.105).
#define B_ 2
#define L_ 4
#define N_ 1024
#define DIM_ 512
#define INNER_ 512
#define HEADS_ 8
#define DH_ 64
#define NS_ 8
#define NFR_ (B_ * L_)            // 8 flat frames
#define ROWS_ (B_ * L_ * N_)      // 8192 point rows

typedef unsigned short u16;
typedef unsigned char u8;
typedef __attribute__((ext_vector_type(8))) short bf16x8;
typedef __attribute__((ext_vector_type(4))) float f32x4;
typedef __attribute__((ext_vector_type(2))) float f32x2;

__device__ inline float bf2f(u16 u) {
    union { unsigned i; float f; } c; c.i = ((unsigned)u) << 16; return c.f;
}
__device__ inline u16 f2bf(float x) {
    __hip_bfloat16 h = __float2bfloat16(x);  // round-to-nearest-even
    return *reinterpret_cast<u16*>(&h);
}

// ---- fp8 e4m3fn helpers (HW cvt on gfx950; manual fallback) ----
#if __has_builtin(__builtin_amdgcn_cvt_pk_f32_fp8) && __has_builtin(__builtin_amdgcn_cvt_pk_fp8_f32)
#define F8_HW 1
#endif

__device__ inline float f8_dec1(unsigned b) {   // manual e4m3fn -> f32
    unsigned e = (b >> 3) & 15, m = b & 7;
    float v;
    if (e == 0) v = (float)m * 0.001953125f;                  // m * 2^-9
    else { union { unsigned i; float f; } c; c.i = ((e + 120u) << 23) | (m << 20); v = c.f; }
    return (b & 0x80) ? -v : v;
}
__device__ inline unsigned f8_enc1(float x) {   // manual f32 -> e4m3fn
    union { float f; unsigned u; } c; c.f = x;
    unsigned s = (c.u >> 31) << 7;
    float a = fabsf(x);
    if (a >= 448.f) return s | 0x7e;
    if (a < 0.015625f) {                        // subnormal: m = round(a*2^9)
        int m = (int)(a * 512.f + 0.5f); if (m > 7) m = 7;
        return s | (unsigned)m;
    }
    int E; float fr = frexpf(a, &E);            // a = fr*2^E, fr in [0.5,1)
    int m4 = (int)(fr * 16.f + 0.5f);           // [8,16]
    int e = E - 1 + 7;
    if (m4 == 16) { m4 = 8; e += 1; }
    if (e >= 16) return s | 0x7e;
    return s | (unsigned)(e << 3) | (unsigned)(m4 - 8);
}
__device__ inline u8 f8_enc(float x) {
#ifdef F8_HW
    return (u8)(__builtin_amdgcn_cvt_pk_fp8_f32(x, 0.f, 0, false) & 0xff);
#else
    return (u8)f8_enc1(x);
#endif
}
__device__ inline void f8_dec2(unsigned w, float& lo, float& hi) {  // low 2 bytes
#ifdef F8_HW
    f32x2 r = __builtin_amdgcn_cvt_pk_f32_fp8((int)w, false);
    lo = r[0]; hi = r[1];
#else
    lo = f8_dec1(w & 0xffu); hi = f8_dec1((w >> 8) & 0xffu);
#endif
}
__device__ inline void f8_dec4(unsigned w, float* o) {              // 4 bytes
#ifdef F8_HW
    f32x2 a = __builtin_amdgcn_cvt_pk_f32_fp8((int)w, false);
    f32x2 b = __builtin_amdgcn_cvt_pk_f32_fp8((int)w, true);
    o[0] = a[0]; o[1] = a[1]; o[2] = b[0]; o[3] = b[1];
#else
    o[0] = f8_dec1(w & 0xffu); o[1] = f8_dec1((w >> 8) & 0xffu);
    o[2] = f8_dec1((w >> 16) & 0xffu); o[3] = f8_dec1(w >> 24);
#endif
}

// Async global->LDS DMA, 16B per lane.  HW writes wave-uniform LDS base +
// lane*16; LDS layout must be linear (rule #21).
__device__ inline void load_lds16(const void* g, void* l) {
    __builtin_amdgcn_global_load_lds(
        (const __attribute__((address_space(1))) unsigned*)g,
        (__attribute__((address_space(3))) unsigned*)l, 16, 0, 0);
}

#define RPAD_(r) ((r) + ((r) >> 4))

// ---------------------------------------------------------------------------
// K0: fused prep kernel — transpose_cvt + layernorm + ball query.
//   blocks [0,256)            : weight transpose+cvt (0..191 wqkv, 192..255 wout)
//   blocks [256, 256+8192)    : LN row (b-256)
//   blocks [8448, 8448+2048)  : ballq block (b-8448)
// ---------------------------------------------------------------------------
__global__ __launch_bounds__(256) void prep_kernel(
    const float* __restrict__ wqkv, const float* __restrict__ wout,
    u16* __restrict__ wqkvT, u16* __restrict__ woutT,
    const float* __restrict__ feat, const float* __restrict__ gamma,
    const float* __restrict__ beta, u16* __restrict__ normf,
    const float* __restrict__ xyz, int* __restrict__ idxt)
{
    __shared__ union {
        float tile[64][65];                               // transpose: 16640 B
        struct { float rx[1088], ry[1088], rz[1088]; } bq; // ballq: 13056 B
        float red[4];                                     // ln
    } sm;

    int blk = blockIdx.x;
    int t = threadIdx.x;

    if (blk < 256) {
        // ---- weight transpose + bf16 cast (64x64 tile, pad 65) ----
        const float* src; u16* dst; int R, C, tr, tc;
        int b = blk;
        if (b < 192) { src = wqkv; dst = wqkvT; R = 512; C = 1536; tr = b / 24; tc = b % 24; }
        else { b -= 192; src = wout; dst = woutT; R = 512; C = 512; tr = b / 8; tc = b % 8; }
        int r0 = tr * 64, c0 = tc * 64;

        int rr = t >> 2, cs = (t & 3) * 16;
        const float* sp = src + (size_t)(r0 + rr) * C + c0 + cs;
        #pragma unroll
        for (int e = 0; e < 16; e += 4) {
            f32x4 v = *(const f32x4*)(sp + e);
            sm.tile[rr][cs + e + 0] = v[0];
            sm.tile[rr][cs + e + 1] = v[1];
            sm.tile[rr][cs + e + 2] = v[2];
            sm.tile[rr][cs + e + 3] = v[3];
        }
        __syncthreads();

        int c = t >> 2, ks = (t & 3) * 16;
        u16 outv[16];
        #pragma unroll
        for (int e = 0; e < 16; ++e) outv[e] = f2bf(sm.tile[ks + e][c]);
        u16* dp = dst + (size_t)(c0 + c) * R + r0 + ks;
        *(bf16x8*)(dp)     = *(bf16x8*)&outv[0];
        *(bf16x8*)(dp + 8) = *(bf16x8*)&outv[8];

    } else if (blk < 256 + ROWS_) {
        // ---- LayerNorm over channel dim (512) -> bf16 ----
        int row = blk - 256;
        const float* fr = feat + (size_t)row * DIM_;
        float x0 = fr[t], x1 = fr[t + 256];

        float s = x0 + x1;
        #pragma unroll
        for (int off = 32; off; off >>= 1) s += __shfl_xor(s, off, 64);
        if ((t & 63) == 0) sm.red[t >> 6] = s;
        __syncthreads();
        float mu = (sm.red[0] + sm.red[1] + sm.red[2] + sm.red[3]) * (1.0f / 512.0f);
        __syncthreads();

        float d0 = x0 - mu, d1 = x1 - mu;
        float q = d0 * d0 + d1 * d1;
        #pragma unroll
        for (int off = 32; off; off >>= 1) q += __shfl_xor(q, off, 64);
        if ((t & 63) == 0) sm.red[t >> 6] = q;
        __syncthreads();
        float var = (sm.red[0] + sm.red[1] + sm.red[2] + sm.red[3]) * (1.0f / 512.0f);
        float inv = rsqrtf(var + 1e-5f);

        normf[(size_t)row * DIM_ + t]       = f2bf(d0 * inv * gamma[t]       + beta[t]);
        normf[(size_t)row * DIM_ + t + 256] = f2bf(d1 * inv * gamma[t + 256] + beta[t + 256]);

    } else {
        // ---- ball query (wave-parallel, staging-amortized) ----
        #pragma clang fp contract(off)
        int bb = blk - (256 + ROWS_);
        int chunk = bb & 255;           // 2048 blocks: (bi*4+jf)*256 + chunk
        int combo = bb >> 8;
        int jf = combo & 3;
        int bi = combo >> 2;

        const float* ref = xyz + (size_t)((bi * L_ + jf) * N_) * 3;
        for (int p = t; p < N_; p += 256) {
            sm.bq.rx[RPAD_(p)] = ref[p * 3 + 0];
            sm.bq.ry[RPAD_(p)] = ref[p * 3 + 1];
            sm.bq.rz[RPAD_(p)] = ref[p * 3 + 2];
        }
        __syncthreads();

        int wave = t >> 6;
        int lane = t & 63;
        int n = chunk * 4 + wave;
        int base = lane * 17;           // RPAD_(lane*16)
        int r0 = lane * 16;

        for (int qi = 0; qi < L_; ++qi) {
            const float* qp = xyz + (size_t)((bi * L_ + qi) * N_ + n) * 3;
            float qx = qp[0], qy = qp[1], qz = qp[2];

            unsigned mask = 0;
            #pragma unroll
            for (int j = 0; j < 16; ++j) {
                float dx = qx - sm.bq.rx[base + j];
                float dy = qy - sm.bq.ry[base + j];
                float dz = qz - sm.bq.rz[base + j];
                float d2 = dx * dx + dy * dy;
                d2 = d2 + dz * dz;
                if (d2 < 0.04f) mask |= (1u << j);
            }

            int cnt = __popc(mask);
            int x = cnt;
            #pragma unroll
            for (int off = 1; off < 64; off <<= 1) {
                int y = __shfl_up(x, off, 64);
                if (lane >= off) x += y;
            }
            int pre = x - cnt;                       // exclusive prefix
            int total = __shfl(x, 63, 64);           // total in-radius count

            int localFirst = mask ? (r0 + __builtin_ctz(mask)) : 0x7fffffff;
            int gfirst = localFirst;
            #pragma unroll
            for (int off = 32; off; off >>= 1) gfirst = min(gfirst, __shfl_xor(gfirst, off, 64));

            int* o = idxt + ((size_t)((qi * B_ + bi) * N_ + n)) * 32 + jf * NS_;

            unsigned m = mask;
            int pos = pre;
            while (m && pos < NS_) {
                int j = __builtin_ctz(m);
                o[pos] = r0 + j;
                m &= m - 1;
                ++pos;
            }
            if (lane == 0) {
                int padv = (total > 0) ? gfirst : 0;
                for (int s = (total < NS_ ? total : NS_); s < NS_; ++s) o[s] = padv;
            }
        }
    }
}

// ---------------------------------------------------------------------------
// K2/K5: MFMA bf16 GEMM, C[M,N] = A[M,K] @ Bt[N,K]^T.
// 8-wave (512-thread) blocks, 128x128 tile, BK=32, double-buffered (r9:
// verified -15 us; 6 waves/SIMD covers the barrier drain).
// Round 17: mode-0 K/V columns (col >= 512) are emitted as fp8 e4m3 into
// kv8[row][K 512B | V 512B] INSTEAD of bf16 (attn gathers from kv8; halves
// gather bytes and makes the per-XCD working set L2-resident).
// mode 0: col<512 -> Cb16 bf16 (Q); col>=512 -> kv8 fp8 (K,V)
// mode 1: Cf32 = gelu(acc + bias) + resid           (final output, f32)
// ---------------------------------------------------------------------------
__global__ __launch_bounds__(512) void gemm_bt(
    const u16* __restrict__ A, const u16* __restrict__ Bt,
    u16* __restrict__ Cb16, float* __restrict__ Cf32,
    int M, int N, int K, int nb128, int mode,
    const float* __restrict__ bias, const float* __restrict__ resid,
    u8* __restrict__ kv8)
{
    __shared__ u16 As[2][128 * 32];   // linear, 2 x 8 KB per operand
    __shared__ u16 Bs[2][128 * 32];

    int bx = blockIdx.x % nb128;
    int by = blockIdx.x / nb128;
    int m0 = by * 128, n0 = bx * 128;
    int t = threadIdx.x;               // 0..511
    int wave = t >> 6, lane = t & 63;
    int lr = lane & 15, quad = lane >> 4;
    int wm = (wave >> 2) * 64;         // 2 waves in M: 0, 64
    int wn = (wave & 3) * 32;          // 4 waves in N: 0, 32, 64, 96

    int rs = t >> 2;
    int kcs = (t & 3) * 8;

    f32x4 acc[4][2];
    #pragma unroll
    for (int i = 0; i < 4; ++i)
        #pragma unroll
        for (int j = 0; j < 2; ++j)
            acc[i][j] = {0.f, 0.f, 0.f, 0.f};

    int NT = K >> 5;                   // 16 K-steps for K=512

    load_lds16(A  + (size_t)(m0 + rs) * K + kcs, &As[0][t * 8]);
    load_lds16(Bt + (size_t)(n0 + rs) * K + kcs, &Bs[0][t * 8]);
    __syncthreads();

    int cur = 0;
    for (int kt = 0; kt < NT; ++kt) {
        if (kt + 1 < NT) {
            int k0 = (kt + 1) << 5;
            load_lds16(A  + (size_t)(m0 + rs) * K + k0 + kcs, &As[cur ^ 1][t * 8]);
            load_lds16(Bt + (size_t)(n0 + rs) * K + k0 + kcs, &Bs[cur ^ 1][t * 8]);
        }

        bf16x8 af[4], bfr[2];
        #pragma unroll
        for (int mb = 0; mb < 4; ++mb)
            af[mb] = *(const bf16x8*)&As[cur][(wm + mb * 16 + lr) * 32 + quad * 8];
        #pragma unroll
        for (int nb = 0; nb < 2; ++nb)
            bfr[nb] = *(const bf16x8*)&Bs[cur][(wn + nb * 16 + lr) * 32 + quad * 8];
        #pragma unroll
        for (int mb = 0; mb < 4; ++mb)
            #pragma unroll
            for (int nb = 0; nb < 2; ++nb)
                acc[mb][nb] = __builtin_amdgcn_mfma_f32_16x16x32_bf16(
                    af[mb], bfr[nb], acc[mb][nb], 0, 0, 0);

        __syncthreads();   // implicit vmcnt(0)+lgkmcnt(0)
        cur ^= 1;
    }

    #pragma unroll
    for (int mb = 0; mb < 4; ++mb) {
        #pragma unroll
        for (int nb = 0; nb < 2; ++nb) {
            int col = n0 + wn + nb * 16 + lr;
            #pragma unroll
            for (int r = 0; r < 4; ++r) {
                int row = m0 + wm + mb * 16 + quad * 4 + r;
                float x = acc[mb][nb][r];
                if (mode == 1) {
                    x += bias[col];
                    float gl = 0.5f * x * (1.0f + erff(x * 0.70710678118654752f));
                    Cf32[(size_t)row * N + col] = gl + resid[(size_t)row * N + col];
                } else if (!kv8 || col < 512) {
                    Cb16[(size_t)row * N + col] = f2bf(x);
                } else {
                    kv8[(size_t)row * 1024 + (col - 512)] = f8_enc(x);
                }
            }
        }
    }
}

// ---------------------------------------------------------------------------
// K4: attention, round 17: fp8 K/V gather.
// r7 analysis: 533 MB of bf16 K/V gathers served at ~15 TB/s (L3) because
// the per-XCD working set (4 frames x 2 MB) exceeds the 4 MB L2.  fp8
// halves bytes (267 MB) and working set (4 MB -> L2-resident); V slot loads
// shrink to one 128B line per wave.  Structure identical to the r3 kernel:
// K row = 512B (8B/lane, dims l*8..l*8+8 like before), decode via HW
// cvt_pk_f32_fp8, dots in f32 fma with Q pre-converted.  Softmax / disp-max
// / PV unchanged.
// ---------------------------------------------------------------------------
__global__ __launch_bounds__(256, 4) void attn_kernel(
    const float* __restrict__ xyz, const u16* __restrict__ qkv,
    const u8* __restrict__ kv8, const int* __restrict__ idxt,
    const float* __restrict__ wsp, u16* __restrict__ fres)
{
    int x = blockIdx.x & 7;             // XCD swizzle retained
    int bi = x >> 2;
    int qi = x & 3;
    int n = blockIdx.x >> 3;

    int t = threadIdx.x;
    int wave = t >> 6, lane = t & 63;

    int qrow = (bi * L_ + qi) * N_ + n;                  // xyz/qkv row
    int qq = (qi * B_ + bi) * N_ + n;                    // idxt row

    __shared__ int grow_s[32];
    __shared__ float nx_s[32], ny_s[32], nz_s[32];
    __shared__ float lg_s[HEADS_][33];                   // pad 33: conflict-free
    __shared__ float a_s[HEADS_][32];
    __shared__ float da_s[HEADS_][3];

    // Per-lane Q fragment: lane l holds q[qrow][l*8 .. l*8+8) -> head l>>3.
    bf16x8 qf = *(const bf16x8*)(qkv + (size_t)qrow * 1536 + lane * 8);
    float qv[8];
    #pragma unroll
    for (int e = 0; e < 8; ++e) qv[e] = bf2f((u16)qf[e]);

    // 32 lanes resolve the gathered rows + neighbor xyz once per block.
    if (t < 32) {
        int idx = idxt[(size_t)qq * 32 + t];             // one coalesced 128B load
        int jf = t >> 3;
        int kr = (bi * L_ + jf) * N_ + idx;
        grow_s[t] = kr;
        nx_s[t] = xyz[(size_t)kr * 3 + 0];
        ny_s[t] = xyz[(size_t)kr * 3 + 1];
        nz_s[t] = xyz[(size_t)kr * 3 + 2];
    }
    __syncthreads();

    // --- QK^T: wave w owns neighbor slots j = w*8 + r.  One coalesced 512B
    // fp8 K-row load per slot (SGPR base + lane*8B), batched before use. ---
    uint2 k8[8];
    #pragma unroll
    for (int r = 0; r < 8; ++r) {
        int kr = __builtin_amdgcn_readfirstlane(grow_s[wave * 8 + r]);
        k8[r] = *(const uint2*)(kv8 + (size_t)kr * 1024 + lane * 8);
    }
    __builtin_amdgcn_sched_barrier(0);   // all 8 row loads issued before use

    #pragma unroll
    for (int r = 0; r < 8; ++r) {
        float kd[8];
        f8_dec4(k8[r].x, &kd[0]);
        f8_dec4(k8[r].y, &kd[4]);
        float p = 0.f;
        #pragma unroll
        for (int e = 0; e < 8; ++e) p += kd[e] * qv[e];
        p += __shfl_xor(p, 1, 64);       // reduce 8-dim partials within the
        p += __shfl_xor(p, 2, 64);       // 8-lane head group -> full dot64
        p += __shfl_xor(p, 4, 64);
        if ((lane & 7) == 0) lg_s[lane >> 3][wave * 8 + r] = p * 0.125f;  // dh^-0.5
    }
    __syncthreads();

    // --- softmax + disp-max in the original (h, j) lane mapping ---
    int hh = lane >> 5;
    int j = lane & 31;
    int h = wave * 2 + hh;

    float lg = lg_s[h][j];
    float mx = lg;
    #pragma unroll
    for (int off = 16; off; off >>= 1) mx = fmaxf(mx, __shfl_xor(mx, off, 64));
    float e = expf(lg - mx);
    float sum = e;
    #pragma unroll
    for (int off = 16; off; off >>= 1) sum += __shfl_xor(sum, off, 64);
    float a = e / sum;
    a_s[h][j] = a;

    float qx = xyz[(size_t)qrow * 3 + 0];
    float qy = xyz[(size_t)qrow * 3 + 1];
    float qz = xyz[(size_t)qrow * 3 + 2];
    float tx = a * (nx_s[j] - qx);
    float ty = a * (ny_s[j] - qy);
    float tz = a * (nz_s[j] - qz);
    #pragma unroll
    for (int off = 16; off; off >>= 1) {
        tx = fmaxf(tx, __shfl_xor(tx, off, 64));
        ty = fmaxf(ty, __shfl_xor(ty, off, 64));
        tz = fmaxf(tz, __shfl_xor(tz, off, 64));
    }
    if (j == 0) { da_s[h][0] = tx; da_s[h][1] = ty; da_s[h][2] = tz; }

    __syncthreads();

    // --- Phase C: V gather, fp8.  lane -> (h, dim pair dd, dd+1); per slot
    // the wave reads one 128B line of V row grow_s[s]. ---
    int dd = j * 2;
    unsigned vboff = 512u + (unsigned)h * 64u + (unsigned)dd;   // byte offset
    unsigned short vv[32];
    #pragma unroll
    for (int s = 0; s < 32; ++s) {
        int r = __builtin_amdgcn_readfirstlane(grow_s[s]);
        vv[s] = *(const unsigned short*)(kv8 + (size_t)r * 1024 + vboff);
    }
    __builtin_amdgcn_sched_barrier(0);   // all 32 loads issued before any use

    float o0 = 0.f, o1 = 0.f;
    #pragma unroll
    for (int s = 0; s < 32; ++s) {
        float at = a_s[h][s];
        float vlo, vhi;
        f8_dec2((unsigned)vv[s], vlo, vhi);
        o0 += at * vlo;
        o1 += at * vhi;
    }
    float dax = da_s[h][0], day = da_s[h][1], daz = da_s[h][2];
    float sp0 = dax * wsp[dd]     + day * wsp[64 + dd]     + daz * wsp[128 + dd];
    float sp1 = dax * wsp[dd + 1] + day * wsp[64 + dd + 1] + daz * wsp[128 + dd + 1];

    u16* op = fres + (size_t)qrow * INNER_ + h * 64 + dd;
    unsigned outw = (unsigned)f2bf(o0 + sp0) | ((unsigned)f2bf(o1 + sp1) << 16);
    *(unsigned*)op = outw;
}

// ---------------------------------------------------------------------------
extern "C" void kernel_launch(void* const* d_in, const int* in_sizes, int n_in,
                              void* d_out, int out_size, void* d_ws, size_t ws_size,
                              hipStream_t stream) {
    const float* xyz   = (const float*)d_in[0];   // (2,4,1024,3)
    const float* feat  = (const float*)d_in[1];   // (2,4,1024,512)
    const float* gamma = (const float*)d_in[2];   // (512)
    const float* beta  = (const float*)d_in[3];   // (512)
    const float* wqkv  = (const float*)d_in[4];   // (512,1536)
    const float* wsp   = (const float*)d_in[5];   // (3,64)
    const float* wout  = (const float*)d_in[6];   // (512,512)
    const float* bout  = (const float*)d_in[7];   // (512)
    float* out = (float*)d_out;

    char* ws = (char*)d_ws;
    u16* normf = (u16*)ws;                 ws += (size_t)ROWS_ * DIM_ * 2;        // 8 MB
    u16* wqkvT = (u16*)ws;                 ws += (size_t)3 * INNER_ * DIM_ * 2;   // 1.5 MB
    u16* woutT = (u16*)ws;                 ws += (size_t)DIM_ * INNER_ * 2;       // 0.5 MB
    u16* qkv   = (u16*)ws;                 ws += (size_t)ROWS_ * 3 * INNER_ * 2;  // 24 MB
    int* idxt  = (int*)ws;                 ws += (size_t)L_ * NFR_ * N_ * NS_ * 4;// 1 MB
    u8*  kv8   = (u8*)ws;                  ws += (size_t)ROWS_ * 1024;            // 8 MB
    u16* fres  = normf;   // alias: normf is dead after GEMM1 completes

    // prep: transpose+cvt (256 blocks) | layernorm (8192) | ball query (2048)
    prep_kernel<<<256 + ROWS_ + 2048, 256, 0, stream>>>(
        wqkv, wout, wqkvT, woutT, feat, gamma, beta, normf, xyz, idxt);
    // qkv = normf @ w_qkv : M=8192, N=1536, K=512  (512-thread blocks)
    // Q cols -> bf16 qkv; K/V cols -> fp8 kv8
    gemm_bt<<<64 * 12, 512, 0, stream>>>(normf, wqkvT, qkv, nullptr,
                                         ROWS_, 3 * INNER_, DIM_, 12, 0, nullptr, nullptr, kv8);
    attn_kernel<<<ROWS_, 256, 0, stream>>>(xyz, qkv, kv8, idxt, wsp, fres);
    // out = gelu(fres @ w_out + b_out) + feature : M=8192, N=512, K=512
    gemm_bt<<<64 * 4, 512, 0, stream>>>(fres, woutT, nullptr, out,
                                        ROWS_, DIM_, INNER_, 4, 1, bout, feat, nullptr);
}